// Round 15
// baseline (163.952 us; speedup 1.0000x reference)
//
#include <hip/hip_runtime.h>
#include <hip/hip_bf16.h>

#define BB 4
#define SS 1024
#define DD 1024
#define HH 16
#define DKK 64

typedef __bf16 bf16;
typedef __bf16 bf16x8 __attribute__((ext_vector_type(8)));
typedef __bf16 bf16x4 __attribute__((ext_vector_type(4)));
typedef float f32x4 __attribute__((ext_vector_type(4)));

#define MFMA(a, b, c) __builtin_amdgcn_mfma_f32_16x16x32_bf16((a), (b), (c), 0, 0, 0)

__device__ __forceinline__ bf16x8 load8(const bf16* p) {
    return *reinterpret_cast<const bf16x8*>(p);
}

// load 8 contiguous f32, convert to bf16x8 in registers
__device__ __forceinline__ bf16x8 load8f(const float* p) {
    f32x4 a = *reinterpret_cast<const f32x4*>(p);
    f32x4 b = *reinterpret_cast<const f32x4*>(p + 4);
    bf16x8 o;
    o[0] = (bf16)a[0]; o[1] = (bf16)a[1]; o[2] = (bf16)a[2]; o[3] = (bf16)a[3];
    o[4] = (bf16)b[0]; o[5] = (bf16)b[1]; o[6] = (bf16)b[2]; o[7] = (bf16)b[3];
    return o;
}

// ---------------------------------------------------------------------------
// 128x128-tile bf16 GEMM, BK=32, reg-staged with fused f32->bf16 conversion
// (cvt kernel deleted; conversion happens during LDS staging).
// MODE 0: A=f32 x, B=f32 Wq|Wk|Wv (selected by n0), writes Q,K [b,h,s,dk]
//         + Vt [b,h,dk,s] bf16.
// MODE 1: A=bf16 ctx ws, B=f32 Wo, writes f32 Out row-major.
// ---------------------------------------------------------------------------
template <int MODE>
__global__ __launch_bounds__(256) void gemm128(const void* __restrict__ Av,
                                               const float* __restrict__ W0,
                                               const float* __restrict__ W1,
                                               const float* __restrict__ W2,
                                               void* __restrict__ o0,
                                               void* __restrict__ o1,
                                               void* __restrict__ o2) {
    const int lane = threadIdx.x & 63;
    const int wave = threadIdx.x >> 6;
    const int wr = wave >> 1, wc = wave & 1;
    const int m0 = blockIdx.x * 128;
    const int n0 = blockIdx.y * 128;
    const int K = DD;

    __shared__ __align__(16) bf16 As[128][32];
    __shared__ __align__(16) bf16 Bs[128][32];

    // staging map: thread t covers rows (t>>2, t>>2+64), 16B chunk t&3
    const int srow = threadIdx.x >> 2;
    const int schk = threadIdx.x & 3;
    const int swz = (schk ^ (srow & 3)) * 8;   // (srow+64)&3 == srow&3

    const int z = n0 >> 10;                    // block-uniform (MODE 0)
    const int nn0 = n0 & 1023;
    const float* W = (z == 0) ? W0 : ((z == 1) ? W1 : W2);

    const float* Bg0 = W + (size_t)(nn0 + srow) * K + schk * 8;
    const float* Bg1 = Bg0 + (size_t)64 * K;

    bf16* Aw0 = &As[srow][swz];
    bf16* Aw1 = &As[srow + 64][swz];
    bf16* Bw0 = &Bs[srow][swz];
    bf16* Bw1 = &Bs[srow + 64][swz];

    // fragment read: data-chunk (lane>>4) stored at position (lane>>4)^(row&3)
    const int rsw = ((lane >> 4) ^ (lane & 3)) * 8;
    const int rrow = lane & 15;

    f32x4 acc[4][4] = {};

    const float* Agf0 = nullptr;
    const float* Agf1 = nullptr;
    const bf16* Agb0 = nullptr;
    const bf16* Agb1 = nullptr;
    bf16x8 ra0, ra1, rb0, rb1;
    if constexpr (MODE == 0) {
        Agf0 = (const float*)Av + (size_t)(m0 + srow) * K + schk * 8;
        Agf1 = Agf0 + (size_t)64 * K;
        ra0 = load8f(Agf0);
        ra1 = load8f(Agf1);
    } else {
        Agb0 = (const bf16*)Av + (size_t)(m0 + srow) * K + schk * 8;
        Agb1 = Agb0 + (size_t)64 * K;
        ra0 = load8(Agb0);
        ra1 = load8(Agb1);
    }
    rb0 = load8f(Bg0);
    rb1 = load8f(Bg1);

    for (int k0 = 0; k0 < K; k0 += 32) {
        __syncthreads();  // WAR: previous iteration's ds_reads complete
        *reinterpret_cast<bf16x8*>(Aw0) = ra0;
        *reinterpret_cast<bf16x8*>(Aw1) = ra1;
        *reinterpret_cast<bf16x8*>(Bw0) = rb0;
        *reinterpret_cast<bf16x8*>(Bw1) = rb1;
        __syncthreads();
        if (k0 + 32 < K) {  // prefetch next K-step into regs
            if constexpr (MODE == 0) {
                ra0 = load8f(Agf0 + k0 + 32);
                ra1 = load8f(Agf1 + k0 + 32);
            } else {
                ra0 = load8(Agb0 + k0 + 32);
                ra1 = load8(Agb1 + k0 + 32);
            }
            rb0 = load8f(Bg0 + k0 + 32);
            rb1 = load8f(Bg1 + k0 + 32);
        }
        bf16x8 af[4], bfr[4];
#pragma unroll
        for (int i = 0; i < 4; i++)
            af[i] = *reinterpret_cast<const bf16x8*>(&As[wr * 64 + i * 16 + rrow][rsw]);
#pragma unroll
        for (int j = 0; j < 4; j++)
            bfr[j] = *reinterpret_cast<const bf16x8*>(&Bs[wc * 64 + j * 16 + rrow][rsw]);
#pragma unroll
        for (int i = 0; i < 4; i++)
#pragma unroll
            for (int j = 0; j < 4; j++)
                acc[i][j] = MFMA(af[i], bfr[j], acc[i][j]);
    }

    if constexpr (MODE == 0) {
        bf16* Qo = (bf16*)o0;
        bf16* Ko = (bf16*)o1;
        bf16* Vto = (bf16*)o2;
#pragma unroll
        for (int i = 0; i < 4; i++)
#pragma unroll
            for (int j = 0; j < 4; j++)
#pragma unroll
                for (int r = 0; r < 4; r++) {
                    int m = m0 + wr * 64 + i * 16 + (lane >> 4) * 4 + r;
                    int n = n0 + wc * 64 + j * 16 + (lane & 15);
                    int b = m >> 10, s = m & 1023;
                    int nn = n & 1023, h = nn >> 6, dk = nn & 63;
                    bf16 v = (bf16)acc[i][j][r];
                    if (z == 0)
                        Qo[(((size_t)(b * HH + h)) * SS + s) * DKK + dk] = v;
                    else if (z == 1)
                        Ko[(((size_t)(b * HH + h)) * SS + s) * DKK + dk] = v;
                    else
                        Vto[(((size_t)(b * HH + h)) * DKK + dk) * SS + s] = v;
                }
    } else {
        float* Out = (float*)o0;
#pragma unroll
        for (int i = 0; i < 4; i++)
#pragma unroll
            for (int j = 0; j < 4; j++)
#pragma unroll
                for (int r = 0; r < 4; r++) {
                    int m = m0 + wr * 64 + i * 16 + (lane >> 4) * 4 + r;
                    int n = n0 + wc * 64 + j * 16 + (lane & 15);
                    Out[(size_t)m * DD + n] = acc[i][j][r];
                }
    }
}

// ---------------------------------------------------------------------------
// attn: round-13 version verbatim (best measured).  Block = 4 waves / 64
// q-rows.  Grid (bh, qbslot): XCD = bh%8 -> K/V L2-local per XCD.  qb
// balanced per CU.  Double-buffered K/V staging, max-free softmax,
// vectorized weight stores, serial strict-upper zero tail.
// ---------------------------------------------------------------------------
__global__ __launch_bounds__(256, 4) void attn(const bf16* __restrict__ Q,
                                               const bf16* __restrict__ K,
                                               const bf16* __restrict__ Vt,
                                               float* __restrict__ Wgt,
                                               bf16* __restrict__ Ctx) {
    const int tid = threadIdx.x;
    const int lane = tid & 63;
    const int wave = tid >> 6;                     // 0..3
    const int bh = blockIdx.x;                     // XCD = bh % 8
    const int qb = (blockIdx.y + (blockIdx.x & 3)) & 15;  // balanced per CU
    const int q0 = qb * 64 + wave * 16;
    const int lr = lane & 15;
    const int g = lane >> 4;
    const int lk8 = g * 8;
    const int rbase = g * 4;
    const int own_diag = q0 >> 4;                  // qb*4 + wave
    const int nch = qb + 1;                        // 64-row K chunks

    const bf16* Qb = Q + (size_t)bh * SS * DKK;
    const bf16* Kb = K + (size_t)bh * SS * DKK;
    const bf16* Vb = Vt + (size_t)bh * DKK * SS;
    float* Wrow = Wgt + ((size_t)bh * SS + q0) * SS;

    __shared__ __align__(16) bf16 Ks[2][64][64];
    __shared__ __align__(16) bf16 Vs[2][64][64];
    __shared__ __align__(16) bf16 Ps[4][16][40];

    const int skr = tid >> 2;
    const int sc0 = tid & 3;
    const int sw0 = (sc0 ^ (skr & 7)) * 8;
    const int sw1 = ((sc0 + 4) ^ (skr & 7)) * 8;

    bf16x8 qa0 = load8(Qb + (size_t)(q0 + lr) * DKK + lk8);
    bf16x8 qa1 = load8(Qb + (size_t)(q0 + lr) * DKK + 32 + lk8);
#pragma unroll
    for (int i = 0; i < 8; i++) {  // fold 1/sqrt(dk)=0.125 into Q (exact pow2)
        qa0[i] = (bf16)((float)qa0[i] * 0.125f);
        qa1[i] = (bf16)((float)qa1[i] * 0.125f);
    }

    const int rsw0 = (g ^ (lr & 7)) * 8;           // swizzled read offsets
    const int rsw1 = ((4 + g) ^ (lr & 7)) * 8;

    float sl[4] = {0.f, 0.f, 0.f, 0.f};

    // ---------------- pass 1: exp-sum (K only, double-buffered) -----------
    {
        bf16x8 ka = load8(Kb + (size_t)skr * DKK + sc0 * 8);
        bf16x8 kb_ = load8(Kb + (size_t)skr * DKK + (sc0 + 4) * 8);
        *reinterpret_cast<bf16x8*>(&Ks[0][skr][sw0]) = ka;
        *reinterpret_cast<bf16x8*>(&Ks[0][skr][sw1]) = kb_;
        __syncthreads();
        for (int ch = 0; ch < nch; ch++) {
            const int cur = ch & 1;
            if (ch + 1 < nch) {
                ka = load8(Kb + (size_t)((ch + 1) * 64 + skr) * DKK + sc0 * 8);
                kb_ = load8(Kb + (size_t)((ch + 1) * 64 + skr) * DKK + (sc0 + 4) * 8);
            }
#pragma unroll
            for (int t = 0; t < 4; t++) {
                const int kt = ch * 4 + t;
                if (kt <= own_diag) {   // wave-uniform
                    bf16x8 kb0 = *reinterpret_cast<const bf16x8*>(&Ks[cur][t * 16 + lr][rsw0]);
                    bf16x8 kb1 = *reinterpret_cast<const bf16x8*>(&Ks[cur][t * 16 + lr][rsw1]);
                    f32x4 sc = {};
                    sc = MFMA(qa0, kb0, sc);
                    sc = MFMA(qa1, kb1, sc);
                    const int kcol = kt * 16 + lr;
#pragma unroll
                    for (int r = 0; r < 4; r++)
                        sl[r] += (kcol <= q0 + rbase + r) ? __expf(sc[r]) : 0.f;
                }
            }
            if (ch + 1 < nch) {
                *reinterpret_cast<bf16x8*>(&Ks[cur ^ 1][skr][sw0]) = ka;
                *reinterpret_cast<bf16x8*>(&Ks[cur ^ 1][skr][sw1]) = kb_;
            }
            __syncthreads();
        }
    }
    float inv[4];
#pragma unroll
    for (int r = 0; r < 4; r++) {  // sum across the 16-lane group
        float t = sl[r];
        t += __shfl_xor(t, 1);
        t += __shfl_xor(t, 2);
        t += __shfl_xor(t, 4);
        t += __shfl_xor(t, 8);
        inv[r] = 1.f / t;
    }

    // ---------------- pass 2: weights write + PV (dbuf K+V) ---------------
    f32x4 oacc[4] = {};
    {
        bf16x8 ka = load8(Kb + (size_t)skr * DKK + sc0 * 8);
        bf16x8 kb_ = load8(Kb + (size_t)skr * DKK + (sc0 + 4) * 8);
        bf16x8 va = load8(Vb + (size_t)skr * SS + sc0 * 8);
        bf16x8 vb_ = load8(Vb + (size_t)skr * SS + (sc0 + 4) * 8);
        *reinterpret_cast<bf16x8*>(&Ks[0][skr][sw0]) = ka;
        *reinterpret_cast<bf16x8*>(&Ks[0][skr][sw1]) = kb_;
        *reinterpret_cast<bf16x8*>(&Vs[0][skr][sw0]) = va;
        *reinterpret_cast<bf16x8*>(&Vs[0][skr][sw1]) = vb_;
        __syncthreads();
        for (int ch = 0; ch < nch; ch++) {
            const int cur = ch & 1;
            if (ch + 1 < nch) {
                ka = load8(Kb + (size_t)((ch + 1) * 64 + skr) * DKK + sc0 * 8);
                kb_ = load8(Kb + (size_t)((ch + 1) * 64 + skr) * DKK + (sc0 + 4) * 8);
                va = load8(Vb + (size_t)skr * SS + (ch + 1) * 64 + sc0 * 8);
                vb_ = load8(Vb + (size_t)skr * SS + (ch + 1) * 64 + (sc0 + 4) * 8);
            }
#pragma unroll
            for (int t = 0; t < 4; t++) {
                const int kt = ch * 4 + t;
                if (kt <= own_diag) {
                    bf16x8 kb0 = *reinterpret_cast<const bf16x8*>(&Ks[cur][t * 16 + lr][rsw0]);
                    bf16x8 kb1 = *reinterpret_cast<const bf16x8*>(&Ks[cur][t * 16 + lr][rsw1]);
                    f32x4 sc = {};
                    sc = MFMA(qa0, kb0, sc);
                    sc = MFMA(qa1, kb1, sc);
                    const int kcol = kt * 16 + lr;
#pragma unroll
                    for (int r = 0; r < 4; r++) {
                        float p = (kcol <= q0 + rbase + r) ? __expf(sc[r]) * inv[r] : 0.f;
                        Ps[wave][rbase + r][(t & 1) * 16 + lr] = (bf16)p;
                    }
                } else {
#pragma unroll
                    for (int r = 0; r < 4; r++)
                        Ps[wave][rbase + r][(t & 1) * 16 + lr] = (bf16)0.f;
                }
                if (t & 1) {
                    // vectorized weight store: lane -> row lane>>2, 8 cols
                    const int colbase = ch * 64 + (t >> 1) * 32;
                    const int prow = lane >> 2;
                    const int pcol = (lane & 3) * 8;
                    bf16x8 pv8 = *reinterpret_cast<const bf16x8*>(&Ps[wave][prow][pcol]);
                    f32x4 w0, w1;
#pragma unroll
                    for (int i = 0; i < 4; i++) {
                        w0[i] = (float)pv8[i];
                        w1[i] = (float)pv8[4 + i];
                    }
                    float* dst = Wrow + (size_t)prow * SS + colbase + pcol;
                    *reinterpret_cast<f32x4*>(dst) = w0;
                    *reinterpret_cast<f32x4*>(dst + 4) = w1;
                    if (kt - 1 <= own_diag) {   // PV over the 32-col pair
                        const int p2 = t >> 1;
                        bf16x8 pf = *reinterpret_cast<const bf16x8*>(&Ps[wave][lr][lk8]);
#pragma unroll
                        for (int j = 0; j < 4; j++) {
                            bf16x8 vb = *reinterpret_cast<const bf16x8*>(
                                &Vs[cur][j * 16 + lr][((4 * p2 + g) ^ (lr & 7)) * 8]);
                            oacc[j] = MFMA(pf, vb, oacc[j]);
                        }
                    }
                }
            }
            if (ch + 1 < nch) {
                *reinterpret_cast<bf16x8*>(&Ks[cur ^ 1][skr][sw0]) = ka;
                *reinterpret_cast<bf16x8*>(&Ks[cur ^ 1][skr][sw1]) = kb_;
                *reinterpret_cast<bf16x8*>(&Vs[cur ^ 1][skr][sw0]) = va;
                *reinterpret_cast<bf16x8*>(&Vs[cur ^ 1][skr][sw1]) = vb_;
            }
            __syncthreads();
        }
    }

    const int b = bh >> 4, h = bh & 15;
#pragma unroll
    for (int j = 0; j < 4; j++)
#pragma unroll
        for (int r = 0; r < 4; r++) {
            int qrow = q0 + rbase + r;
            int col = h * 64 + j * 16 + lr;
            Ctx[((size_t)b * SS + qrow) * DD + col] = (bf16)oacc[j][r];
        }

    // ---------------- tail: strict-upper zeros (zfill folded in) ----------
    const int zc0 = nch * 64;
    if (zc0 < SS) {
        const int nc4 = (SS - zc0) >> 2;
        float* zbase = Wgt + ((size_t)bh * SS + qb * 64) * SS + zc0;
        const f32x4 z = {0.f, 0.f, 0.f, 0.f};
        for (int r = 0; r < 64; r++)
            for (int c = tid; c < nc4; c += 256)
                reinterpret_cast<f32x4*>(zbase + (size_t)r * SS)[c] = z;
    }
}

// ---------------------------------------------------------------------------
extern "C" void kernel_launch(void* const* d_in, const int* in_sizes, int n_in,
                              void* d_out, int out_size, void* d_ws, size_t ws_size,
                              hipStream_t stream) {
    const float* x  = (const float*)d_in[0];
    const float* Wq = (const float*)d_in[1];
    const float* Wk = (const float*)d_in[2];
    const float* Wv = (const float*)d_in[3];
    const float* Wo = (const float*)d_in[4];

    float* out = (float*)d_out;                     // output (B,S,D) f32
    float* wgt = out + (size_t)BB * SS * DD;        // weights (B,H,S,S) f32

    const size_t MEG = 1024 * 1024;
    bf16* qws = (bf16*)d_ws;          // Q  [b,h,s,dk]   8 MB
    bf16* kws = qws + 4 * MEG;        // K  [b,h,s,dk]   8 MB
    bf16* vws = kws + 4 * MEG;        // Vt [b,h,dk,s]   8 MB
    bf16* cws = vws + 4 * MEG;        // concat ctx [b,s,d]  8 MB

    gemm128<0><<<dim3(32, 24), 256, 0, stream>>>(x, Wq, Wk, Wv, qws, kws, vws);
    attn<<<dim3(64, 16), 256, 0, stream>>>(qws, kws, vws, wgt, cws);
    gemm128<1><<<dim3(32, 8), 256, 0, stream>>>(cws, Wo, nullptr, nullptr,
                                                out, nullptr, nullptr);
}

// Round 16
// 147.227 us; speedup vs baseline: 1.1136x; 1.1136x over previous
//
#include <hip/hip_runtime.h>
#include <hip/hip_bf16.h>

#define BB 4
#define SS 1024
#define DD 1024
#define HH 16
#define DKK 64

typedef __bf16 bf16;
typedef __bf16 bf16x8 __attribute__((ext_vector_type(8)));
typedef __bf16 bf16x4 __attribute__((ext_vector_type(4)));
typedef float f32x4 __attribute__((ext_vector_type(4)));

#define MFMA(a, b, c) __builtin_amdgcn_mfma_f32_16x16x32_bf16((a), (b), (c), 0, 0, 0)

__device__ __forceinline__ bf16x8 load8(const bf16* p) {
    return *reinterpret_cast<const bf16x8*>(p);
}

// async global->LDS 16B: per-lane global src, wave-uniform LDS base + lane*16
__device__ __forceinline__ void gload16(const bf16* g, bf16* l) {
    __builtin_amdgcn_global_load_lds(
        (const __attribute__((address_space(1))) void*)g,
        (__attribute__((address_space(3))) void*)l, 16, 0, 0);
}

// ---------------------------------------------------------------------------
// Kernel 0: f32 -> bf16 conversion (convert ONCE; GEMMs re-read panels many
// times, so converting inside the GEMM doubles re-read traffic - r15 lesson).
//   [0,4M): x   [4M,7M): Wq|Wk|Wv concat   [7M,8M): Wo
// ---------------------------------------------------------------------------
__global__ __launch_bounds__(256) void cvt_bf16(const float* __restrict__ x,
                                                const float* __restrict__ Wq,
                                                const float* __restrict__ Wk,
                                                const float* __restrict__ Wv,
                                                const float* __restrict__ Wo,
                                                bf16* __restrict__ dst) {
    const size_t MEG = 1024 * 1024;
    size_t e = ((size_t)blockIdx.x * 256 + threadIdx.x) * 4;
    const float* src;
    size_t off;
    if (e < 4 * MEG)      { src = x;  off = e; }
    else if (e < 5 * MEG) { src = Wq; off = e - 4 * MEG; }
    else if (e < 6 * MEG) { src = Wk; off = e - 5 * MEG; }
    else if (e < 7 * MEG) { src = Wv; off = e - 6 * MEG; }
    else                  { src = Wo; off = e - 7 * MEG; }
    f32x4 v = *reinterpret_cast<const f32x4*>(src + off);
    bf16x4 o;
    o[0] = (bf16)v[0]; o[1] = (bf16)v[1]; o[2] = (bf16)v[2]; o[3] = (bf16)v[3];
    *reinterpret_cast<bf16x4*>(dst + e) = o;
}

// ---------------------------------------------------------------------------
// 128x128-tile bf16 GEMM, m97 structure: global_load_lds width-16 staging,
// linear LDS dest + inverse-swizzled GLOBAL source + swizzled read.
// MODE 0: N=3072 (Wq|Wk|Wv), writes Q,K [b,h,s,dk] + Vt [b,h,dk,s] bf16.
//         Epilogue also writes the weights' strict-upper zero bands (126 MB)
//         using the otherwise-idle store pipe; stores sit AFTER the K-loop so
//         they cannot pollute the per-barrier vmcnt drain (r14 lesson).
// MODE 1: N=1024, writes f32 Out row-major.
// ---------------------------------------------------------------------------
template <int MODE>
__global__ __launch_bounds__(256) void gemm128(const bf16* __restrict__ A,
                                               const bf16* __restrict__ Bm,
                                               void* __restrict__ o0,
                                               void* __restrict__ o1,
                                               void* __restrict__ o2,
                                               float* __restrict__ Wgt) {
    const int lane = threadIdx.x & 63;
    const int wave = threadIdx.x >> 6;
    const int wr = wave >> 1, wc = wave & 1;
    const int m0 = blockIdx.x * 128;
    const int n0 = blockIdx.y * 128;
    const int K = DD;

    __shared__ __align__(16) bf16 As[128][32];
    __shared__ __align__(16) bf16 Bs[128][32];

    const int r0 = wave * 32 + (lane >> 2);
    const int r1 = r0 + 16;
    const int csw = ((lane & 3) ^ (r0 & 3)) * 8;

    const bf16* Ag0 = A + (size_t)(m0 + r0) * K + csw;
    const bf16* Ag1 = A + (size_t)(m0 + r1) * K + csw;
    const bf16* Bg0 = Bm + (size_t)(n0 + r0) * K + csw;
    const bf16* Bg1 = Bm + (size_t)(n0 + r1) * K + csw;
    bf16* Aw0 = &As[wave * 32][0];
    bf16* Aw1 = &As[wave * 32 + 16][0];
    bf16* Bw0 = &Bs[wave * 32][0];
    bf16* Bw1 = &Bs[wave * 32 + 16][0];

    const int rsw = ((lane >> 4) ^ (lane & 3)) * 8;
    const int rrow = lane & 15;

    f32x4 acc[4][4] = {};

    for (int k0 = 0; k0 < K; k0 += 32) {
        __syncthreads();
        gload16(Ag0 + k0, Aw0);
        gload16(Ag1 + k0, Aw1);
        gload16(Bg0 + k0, Bw0);
        gload16(Bg1 + k0, Bw1);
        __syncthreads();
        bf16x8 af[4], bfr[4];
#pragma unroll
        for (int i = 0; i < 4; i++)
            af[i] = *reinterpret_cast<const bf16x8*>(&As[wr * 64 + i * 16 + rrow][rsw]);
#pragma unroll
        for (int j = 0; j < 4; j++)
            bfr[j] = *reinterpret_cast<const bf16x8*>(&Bs[wc * 64 + j * 16 + rrow][rsw]);
#pragma unroll
        for (int i = 0; i < 4; i++)
#pragma unroll
            for (int j = 0; j < 4; j++)
                acc[i][j] = MFMA(af[i], bfr[j], acc[i][j]);
    }

    if constexpr (MODE == 0) {
        bf16* Qo = (bf16*)o0;
        bf16* Ko = (bf16*)o1;
        bf16* Vto = (bf16*)o2;
        const int z = n0 >> 10;
#pragma unroll
        for (int i = 0; i < 4; i++)
#pragma unroll
            for (int j = 0; j < 4; j++)
#pragma unroll
                for (int r = 0; r < 4; r++) {
                    int m = m0 + wr * 64 + i * 16 + (lane >> 4) * 4 + r;
                    int n = n0 + wc * 64 + j * 16 + (lane & 15);
                    int b = m >> 10, s = m & 1023;
                    int nn = n & 1023, h = nn >> 6, dk = nn & 63;
                    bf16 v = (bf16)acc[i][j][r];
                    if (z == 0)
                        Qo[(((size_t)(b * HH + h)) * SS + s) * DKK + dk] = v;
                    else if (z == 1)
                        Ko[(((size_t)(b * HH + h)) * SS + s) * DKK + dk] = v;
                    else
                        Vto[(((size_t)(b * HH + h)) * DKK + dk) * SS + s] = v;
                }
        // ---- zero-fill epilogue: 1024 (bh,qb) bands grid-strided over 768
        // blocks; band (bh,qb) = rows [qb*64,qb*64+64) x cols [(qb+1)*64,1024)
        const int bid = blockIdx.y * 32 + blockIdx.x;
        const int zrow = threadIdx.x >> 2;
        const int zcl = threadIdx.x & 3;
        const f32x4 z4 = {0.f, 0.f, 0.f, 0.f};
        for (int band = bid; band < 1024; band += 768) {
            const int bh = band >> 4, qb = band & 15;
            const int c0 = (qb + 1) * 64;
            const int nc4 = (1024 - c0) >> 2;
            if (nc4 <= 0) continue;
            float* rp = Wgt + ((size_t)bh * SS + qb * 64 + zrow) * SS + c0;
            for (int c = zcl; c < nc4; c += 4)
                *reinterpret_cast<f32x4*>(rp + c * 4) = z4;
        }
    } else {
        float* Out = (float*)o0;
#pragma unroll
        for (int i = 0; i < 4; i++)
#pragma unroll
            for (int j = 0; j < 4; j++)
#pragma unroll
                for (int r = 0; r < 4; r++) {
                    int m = m0 + wr * 64 + i * 16 + (lane >> 4) * 4 + r;
                    int n = n0 + wc * 64 + j * 16 + (lane & 15);
                    Out[(size_t)m * DD + n] = acc[i][j][r];
                }
    }
}

// ---------------------------------------------------------------------------
// attn: round-13 version, minus the zero tail (now done by gemm0's epilogue).
// Block = 4 waves / 64 q-rows.  Grid (bh, qbslot): XCD = bh%8 -> K/V L2-local.
// qb balanced per CU.  Double-buffered K/V staging, max-free softmax,
// vectorized weight stores.
// ---------------------------------------------------------------------------
__global__ __launch_bounds__(256, 4) void attn(const bf16* __restrict__ Q,
                                               const bf16* __restrict__ K,
                                               const bf16* __restrict__ Vt,
                                               float* __restrict__ Wgt,
                                               bf16* __restrict__ Ctx) {
    const int tid = threadIdx.x;
    const int lane = tid & 63;
    const int wave = tid >> 6;                     // 0..3
    const int bh = blockIdx.x;                     // XCD = bh % 8
    const int qb = (blockIdx.y + (blockIdx.x & 3)) & 15;  // balanced per CU
    const int q0 = qb * 64 + wave * 16;
    const int lr = lane & 15;
    const int g = lane >> 4;
    const int lk8 = g * 8;
    const int rbase = g * 4;
    const int own_diag = q0 >> 4;                  // qb*4 + wave
    const int nch = qb + 1;                        // 64-row K chunks

    const bf16* Qb = Q + (size_t)bh * SS * DKK;
    const bf16* Kb = K + (size_t)bh * SS * DKK;
    const bf16* Vb = Vt + (size_t)bh * DKK * SS;
    float* Wrow = Wgt + ((size_t)bh * SS + q0) * SS;

    __shared__ __align__(16) bf16 Ks[2][64][64];
    __shared__ __align__(16) bf16 Vs[2][64][64];
    __shared__ __align__(16) bf16 Ps[4][16][40];

    const int skr = tid >> 2;
    const int sc0 = tid & 3;
    const int sw0 = (sc0 ^ (skr & 7)) * 8;
    const int sw1 = ((sc0 + 4) ^ (skr & 7)) * 8;

    bf16x8 qa0 = load8(Qb + (size_t)(q0 + lr) * DKK + lk8);
    bf16x8 qa1 = load8(Qb + (size_t)(q0 + lr) * DKK + 32 + lk8);
#pragma unroll
    for (int i = 0; i < 8; i++) {  // fold 1/sqrt(dk)=0.125 into Q (exact pow2)
        qa0[i] = (bf16)((float)qa0[i] * 0.125f);
        qa1[i] = (bf16)((float)qa1[i] * 0.125f);
    }

    const int rsw0 = (g ^ (lr & 7)) * 8;           // swizzled read offsets
    const int rsw1 = ((4 + g) ^ (lr & 7)) * 8;

    float sl[4] = {0.f, 0.f, 0.f, 0.f};

    // ---------------- pass 1: exp-sum (K only, double-buffered) -----------
    {
        bf16x8 ka = load8(Kb + (size_t)skr * DKK + sc0 * 8);
        bf16x8 kb_ = load8(Kb + (size_t)skr * DKK + (sc0 + 4) * 8);
        *reinterpret_cast<bf16x8*>(&Ks[0][skr][sw0]) = ka;
        *reinterpret_cast<bf16x8*>(&Ks[0][skr][sw1]) = kb_;
        __syncthreads();
        for (int ch = 0; ch < nch; ch++) {
            const int cur = ch & 1;
            if (ch + 1 < nch) {
                ka = load8(Kb + (size_t)((ch + 1) * 64 + skr) * DKK + sc0 * 8);
                kb_ = load8(Kb + (size_t)((ch + 1) * 64 + skr) * DKK + (sc0 + 4) * 8);
            }
#pragma unroll
            for (int t = 0; t < 4; t++) {
                const int kt = ch * 4 + t;
                if (kt <= own_diag) {   // wave-uniform
                    bf16x8 kb0 = *reinterpret_cast<const bf16x8*>(&Ks[cur][t * 16 + lr][rsw0]);
                    bf16x8 kb1 = *reinterpret_cast<const bf16x8*>(&Ks[cur][t * 16 + lr][rsw1]);
                    f32x4 sc = {};
                    sc = MFMA(qa0, kb0, sc);
                    sc = MFMA(qa1, kb1, sc);
                    const int kcol = kt * 16 + lr;
#pragma unroll
                    for (int r = 0; r < 4; r++)
                        sl[r] += (kcol <= q0 + rbase + r) ? __expf(sc[r]) : 0.f;
                }
            }
            if (ch + 1 < nch) {
                *reinterpret_cast<bf16x8*>(&Ks[cur ^ 1][skr][sw0]) = ka;
                *reinterpret_cast<bf16x8*>(&Ks[cur ^ 1][skr][sw1]) = kb_;
            }
            __syncthreads();
        }
    }
    float inv[4];
#pragma unroll
    for (int r = 0; r < 4; r++) {  // sum across the 16-lane group
        float t = sl[r];
        t += __shfl_xor(t, 1);
        t += __shfl_xor(t, 2);
        t += __shfl_xor(t, 4);
        t += __shfl_xor(t, 8);
        inv[r] = 1.f / t;
    }

    // ---------------- pass 2: weights write + PV (dbuf K+V) ---------------
    f32x4 oacc[4] = {};
    {
        bf16x8 ka = load8(Kb + (size_t)skr * DKK + sc0 * 8);
        bf16x8 kb_ = load8(Kb + (size_t)skr * DKK + (sc0 + 4) * 8);
        bf16x8 va = load8(Vb + (size_t)skr * SS + sc0 * 8);
        bf16x8 vb_ = load8(Vb + (size_t)skr * SS + (sc0 + 4) * 8);
        *reinterpret_cast<bf16x8*>(&Ks[0][skr][sw0]) = ka;
        *reinterpret_cast<bf16x8*>(&Ks[0][skr][sw1]) = kb_;
        *reinterpret_cast<bf16x8*>(&Vs[0][skr][sw0]) = va;
        *reinterpret_cast<bf16x8*>(&Vs[0][skr][sw1]) = vb_;
        __syncthreads();
        for (int ch = 0; ch < nch; ch++) {
            const int cur = ch & 1;
            if (ch + 1 < nch) {
                ka = load8(Kb + (size_t)((ch + 1) * 64 + skr) * DKK + sc0 * 8);
                kb_ = load8(Kb + (size_t)((ch + 1) * 64 + skr) * DKK + (sc0 + 4) * 8);
                va = load8(Vb + (size_t)skr * SS + (ch + 1) * 64 + sc0 * 8);
                vb_ = load8(Vb + (size_t)skr * SS + (ch + 1) * 64 + (sc0 + 4) * 8);
            }
#pragma unroll
            for (int t = 0; t < 4; t++) {
                const int kt = ch * 4 + t;
                if (kt <= own_diag) {
                    bf16x8 kb0 = *reinterpret_cast<const bf16x8*>(&Ks[cur][t * 16 + lr][rsw0]);
                    bf16x8 kb1 = *reinterpret_cast<const bf16x8*>(&Ks[cur][t * 16 + lr][rsw1]);
                    f32x4 sc = {};
                    sc = MFMA(qa0, kb0, sc);
                    sc = MFMA(qa1, kb1, sc);
                    const int kcol = kt * 16 + lr;
#pragma unroll
                    for (int r = 0; r < 4; r++) {
                        float p = (kcol <= q0 + rbase + r) ? __expf(sc[r]) * inv[r] : 0.f;
                        Ps[wave][rbase + r][(t & 1) * 16 + lr] = (bf16)p;
                    }
                } else {
#pragma unroll
                    for (int r = 0; r < 4; r++)
                        Ps[wave][rbase + r][(t & 1) * 16 + lr] = (bf16)0.f;
                }
                if (t & 1) {
                    // vectorized weight store: lane -> row lane>>2, 8 cols
                    const int colbase = ch * 64 + (t >> 1) * 32;
                    const int prow = lane >> 2;
                    const int pcol = (lane & 3) * 8;
                    bf16x8 pv8 = *reinterpret_cast<const bf16x8*>(&Ps[wave][prow][pcol]);
                    f32x4 w0, w1;
#pragma unroll
                    for (int i = 0; i < 4; i++) {
                        w0[i] = (float)pv8[i];
                        w1[i] = (float)pv8[4 + i];
                    }
                    float* dst = Wrow + (size_t)prow * SS + colbase + pcol;
                    *reinterpret_cast<f32x4*>(dst) = w0;
                    *reinterpret_cast<f32x4*>(dst + 4) = w1;
                    if (kt - 1 <= own_diag) {   // PV over the 32-col pair
                        const int p2 = t >> 1;
                        bf16x8 pf = *reinterpret_cast<const bf16x8*>(&Ps[wave][lr][lk8]);
#pragma unroll
                        for (int j = 0; j < 4; j++) {
                            bf16x8 vb = *reinterpret_cast<const bf16x8*>(
                                &Vs[cur][j * 16 + lr][((4 * p2 + g) ^ (lr & 7)) * 8]);
                            oacc[j] = MFMA(pf, vb, oacc[j]);
                        }
                    }
                }
            }
            if (ch + 1 < nch) {
                *reinterpret_cast<bf16x8*>(&Ks[cur ^ 1][skr][sw0]) = ka;
                *reinterpret_cast<bf16x8*>(&Ks[cur ^ 1][skr][sw1]) = kb_;
                *reinterpret_cast<bf16x8*>(&Vs[cur ^ 1][skr][sw0]) = va;
                *reinterpret_cast<bf16x8*>(&Vs[cur ^ 1][skr][sw1]) = vb_;
            }
            __syncthreads();
        }
    }

    const int b = bh >> 4, h = bh & 15;
#pragma unroll
    for (int j = 0; j < 4; j++)
#pragma unroll
        for (int r = 0; r < 4; r++) {
            int qrow = q0 + rbase + r;
            int col = h * 64 + j * 16 + lr;
            Ctx[((size_t)b * SS + qrow) * DD + col] = (bf16)oacc[j][r];
        }
}

// ---------------------------------------------------------------------------
extern "C" void kernel_launch(void* const* d_in, const int* in_sizes, int n_in,
                              void* d_out, int out_size, void* d_ws, size_t ws_size,
                              hipStream_t stream) {
    const float* x  = (const float*)d_in[0];
    const float* Wq = (const float*)d_in[1];
    const float* Wk = (const float*)d_in[2];
    const float* Wv = (const float*)d_in[3];
    const float* Wo = (const float*)d_in[4];

    float* out = (float*)d_out;                     // output (B,S,D) f32
    float* wgt = out + (size_t)BB * SS * DD;        // weights (B,H,S,S) f32

    const size_t MEG = 1024 * 1024;
    bf16* xb   = (bf16*)d_ws;         // x bf16        [0,4M)
    bf16* wcat = xb + 4 * MEG;        // Wq|Wk|Wv bf16 [4M,7M)
    bf16* wob  = xb + 7 * MEG;        // Wo bf16       [7M,8M)
    bf16* qws  = xb + 8 * MEG;        // Q  [b,h,s,dk]
    bf16* kws  = xb + 12 * MEG;       // K  [b,h,s,dk]
    bf16* vws  = xb + 16 * MEG;       // Vt [b,h,dk,s]
    bf16* cws  = xb + 20 * MEG;       // concat ctx [b,s,d]

    cvt_bf16<<<dim3(8192), 256, 0, stream>>>(x, Wq, Wk, Wv, Wo, xb);
    gemm128<0><<<dim3(32, 24), 256, 0, stream>>>(xb, wcat, qws, kws, vws, wgt);
    attn<<<dim3(64, 16), 256, 0, stream>>>(qws, kws, vws, wgt, cws);
    gemm128<1><<<dim3(32, 8), 256, 0, stream>>>(cws, wob, out, nullptr, nullptr,
                                                nullptr);
}

// Round 17
// 143.906 us; speedup vs baseline: 1.1393x; 1.0231x over previous
//
#include <hip/hip_runtime.h>
#include <hip/hip_bf16.h>

#define BB 4
#define SS 1024
#define DD 1024
#define HH 16
#define DKK 64

typedef __bf16 bf16;
typedef __bf16 bf16x8 __attribute__((ext_vector_type(8)));
typedef __bf16 bf16x4 __attribute__((ext_vector_type(4)));
typedef float f32x4 __attribute__((ext_vector_type(4)));

#define MFMA(a, b, c) __builtin_amdgcn_mfma_f32_16x16x32_bf16((a), (b), (c), 0, 0, 0)

__device__ __forceinline__ bf16x8 load8(const bf16* p) {
    return *reinterpret_cast<const bf16x8*>(p);
}

// async global->LDS 16B: per-lane global src, wave-uniform LDS base + lane*16
__device__ __forceinline__ void gload16(const bf16* g, bf16* l) {
    __builtin_amdgcn_global_load_lds(
        (const __attribute__((address_space(1))) void*)g,
        (__attribute__((address_space(3))) void*)l, 16, 0, 0);
}

// ---------------------------------------------------------------------------
// Kernel 0: f32 -> bf16 conversion (convert ONCE - r15 lesson).
//   [0,4M): x   [4M,7M): Wq|Wk|Wv concat   [7M,8M): Wo
// ---------------------------------------------------------------------------
__global__ __launch_bounds__(256) void cvt_bf16(const float* __restrict__ x,
                                                const float* __restrict__ Wq,
                                                const float* __restrict__ Wk,
                                                const float* __restrict__ Wv,
                                                const float* __restrict__ Wo,
                                                bf16* __restrict__ dst) {
    const size_t MEG = 1024 * 1024;
    size_t e = ((size_t)blockIdx.x * 256 + threadIdx.x) * 4;
    const float* src;
    size_t off;
    if (e < 4 * MEG)      { src = x;  off = e; }
    else if (e < 5 * MEG) { src = Wq; off = e - 4 * MEG; }
    else if (e < 6 * MEG) { src = Wk; off = e - 5 * MEG; }
    else if (e < 7 * MEG) { src = Wv; off = e - 6 * MEG; }
    else                  { src = Wo; off = e - 7 * MEG; }
    f32x4 v = *reinterpret_cast<const f32x4*>(src + off);
    bf16x4 o;
    o[0] = (bf16)v[0]; o[1] = (bf16)v[1]; o[2] = (bf16)v[2]; o[3] = (bf16)v[3];
    *reinterpret_cast<bf16x4*>(dst + e) = o;
}

// ---------------------------------------------------------------------------
// gemm128 (MODE 0 only): 128x128-tile, m97 structure, gload_lds staging.
// Writes Q,K [b,h,s,dk] + Vt [b,h,dk,s] bf16.  Epilogue grid-strides the
// weights' strict-upper zero bands (126 MB) after the K-loop (r16, neutral
// placement - kept here to keep attn lean).
// ---------------------------------------------------------------------------
__global__ __launch_bounds__(256) void gemm_qkv(const bf16* __restrict__ A,
                                                const bf16* __restrict__ Bm,
                                                bf16* __restrict__ Qo,
                                                bf16* __restrict__ Ko,
                                                bf16* __restrict__ Vto,
                                                float* __restrict__ Wgt) {
    const int lane = threadIdx.x & 63;
    const int wave = threadIdx.x >> 6;
    const int wr = wave >> 1, wc = wave & 1;
    const int m0 = blockIdx.x * 128;
    const int n0 = blockIdx.y * 128;
    const int K = DD;

    __shared__ __align__(16) bf16 As[128][32];
    __shared__ __align__(16) bf16 Bs[128][32];

    const int r0 = wave * 32 + (lane >> 2);
    const int r1 = r0 + 16;
    const int csw = ((lane & 3) ^ (r0 & 3)) * 8;

    const bf16* Ag0 = A + (size_t)(m0 + r0) * K + csw;
    const bf16* Ag1 = A + (size_t)(m0 + r1) * K + csw;
    const bf16* Bg0 = Bm + (size_t)(n0 + r0) * K + csw;
    const bf16* Bg1 = Bm + (size_t)(n0 + r1) * K + csw;
    bf16* Aw0 = &As[wave * 32][0];
    bf16* Aw1 = &As[wave * 32 + 16][0];
    bf16* Bw0 = &Bs[wave * 32][0];
    bf16* Bw1 = &Bs[wave * 32 + 16][0];

    const int rsw = ((lane >> 4) ^ (lane & 3)) * 8;
    const int rrow = lane & 15;

    f32x4 acc[4][4] = {};

    for (int k0 = 0; k0 < K; k0 += 32) {
        __syncthreads();
        gload16(Ag0 + k0, Aw0);
        gload16(Ag1 + k0, Aw1);
        gload16(Bg0 + k0, Bw0);
        gload16(Bg1 + k0, Bw1);
        __syncthreads();
        bf16x8 af[4], bfr[4];
#pragma unroll
        for (int i = 0; i < 4; i++)
            af[i] = *reinterpret_cast<const bf16x8*>(&As[wr * 64 + i * 16 + rrow][rsw]);
#pragma unroll
        for (int j = 0; j < 4; j++)
            bfr[j] = *reinterpret_cast<const bf16x8*>(&Bs[wc * 64 + j * 16 + rrow][rsw]);
#pragma unroll
        for (int i = 0; i < 4; i++)
#pragma unroll
            for (int j = 0; j < 4; j++)
                acc[i][j] = MFMA(af[i], bfr[j], acc[i][j]);
    }

    const int z = n0 >> 10;
#pragma unroll
    for (int i = 0; i < 4; i++)
#pragma unroll
        for (int j = 0; j < 4; j++)
#pragma unroll
            for (int r = 0; r < 4; r++) {
                int m = m0 + wr * 64 + i * 16 + (lane >> 4) * 4 + r;
                int n = n0 + wc * 64 + j * 16 + (lane & 15);
                int b = m >> 10, s = m & 1023;
                int nn = n & 1023, h = nn >> 6, dk = nn & 63;
                bf16 v = (bf16)acc[i][j][r];
                if (z == 0)
                    Qo[(((size_t)(b * HH + h)) * SS + s) * DKK + dk] = v;
                else if (z == 1)
                    Ko[(((size_t)(b * HH + h)) * SS + s) * DKK + dk] = v;
                else
                    Vto[(((size_t)(b * HH + h)) * DKK + dk) * SS + s] = v;
            }
    // ---- zero-fill epilogue: 1024 (bh,qb) bands grid-strided over 768 blocks
    const int bid = blockIdx.y * 32 + blockIdx.x;
    const int zrow = threadIdx.x >> 2;
    const int zcl = threadIdx.x & 3;
    const f32x4 z4 = {0.f, 0.f, 0.f, 0.f};
    for (int band = bid; band < 1024; band += 768) {
        const int bh = band >> 4, qb = band & 15;
        const int c0 = (qb + 1) * 64;
        const int nc4 = (1024 - c0) >> 2;
        if (nc4 <= 0) continue;
        float* rp = Wgt + ((size_t)bh * SS + qb * 64 + zrow) * SS + c0;
        for (int c = zcl; c < nc4; c += 4)
            *reinterpret_cast<f32x4*>(rp + c * 4) = z4;
    }
}

// ---------------------------------------------------------------------------
// gemm64: 64x64-tile GEMM for the output projection (N=1024).  128^2 tiles
// gave grid (32,8)=256 blocks = 1 block/CU = 12.5% occupancy (grid-starved,
// latency-bound).  64^2 -> grid (64,16) = 1024 blocks = 4/CU = 16 waves/CU.
// Same staging/swizzle algebra (row = 64B in both layouts).  f32 output.
// ---------------------------------------------------------------------------
__global__ __launch_bounds__(256) void gemm_out(const bf16* __restrict__ A,
                                                const bf16* __restrict__ Bm,
                                                float* __restrict__ Out) {
    const int lane = threadIdx.x & 63;
    const int wave = threadIdx.x >> 6;
    const int wr = wave >> 1, wc = wave & 1;
    const int m0 = blockIdx.x * 64;
    const int n0 = blockIdx.y * 64;
    const int K = DD;

    __shared__ __align__(16) bf16 As[64][32];
    __shared__ __align__(16) bf16 Bs[64][32];

    // staging: wave w stages rows [w*16, w*16+16) of A and B (1 gload16 each)
    const int srow = wave * 16 + (lane >> 2);
    const int csw = ((lane & 3) ^ (srow & 3)) * 8;
    const bf16* Ag = A + (size_t)(m0 + srow) * K + csw;
    const bf16* Bg = Bm + (size_t)(n0 + srow) * K + csw;
    bf16* Aw = &As[wave * 16][0];
    bf16* Bw = &Bs[wave * 16][0];

    const int rsw = ((lane >> 4) ^ (lane & 3)) * 8;
    const int rrow = lane & 15;

    f32x4 acc[2][2] = {};

    for (int k0 = 0; k0 < K; k0 += 32) {
        __syncthreads();
        gload16(Ag + k0, Aw);
        gload16(Bg + k0, Bw);
        __syncthreads();
        bf16x8 af[2], bfr[2];
#pragma unroll
        for (int i = 0; i < 2; i++)
            af[i] = *reinterpret_cast<const bf16x8*>(&As[wr * 32 + i * 16 + rrow][rsw]);
#pragma unroll
        for (int j = 0; j < 2; j++)
            bfr[j] = *reinterpret_cast<const bf16x8*>(&Bs[wc * 32 + j * 16 + rrow][rsw]);
#pragma unroll
        for (int i = 0; i < 2; i++)
#pragma unroll
            for (int j = 0; j < 2; j++)
                acc[i][j] = MFMA(af[i], bfr[j], acc[i][j]);
    }

#pragma unroll
    for (int i = 0; i < 2; i++)
#pragma unroll
        for (int j = 0; j < 2; j++)
#pragma unroll
            for (int r = 0; r < 4; r++) {
                int m = m0 + wr * 32 + i * 16 + (lane >> 4) * 4 + r;
                int n = n0 + wc * 32 + j * 16 + (lane & 15);
                Out[(size_t)m * DD + n] = acc[i][j][r];
            }
}

// ---------------------------------------------------------------------------
// attn: r16 version + T5 setprio(1) around MFMA clusters (m191 regime:
// co-resident blocks at different qb phases -> scheduler arbitration pays).
// ---------------------------------------------------------------------------
__global__ __launch_bounds__(256, 4) void attn(const bf16* __restrict__ Q,
                                               const bf16* __restrict__ K,
                                               const bf16* __restrict__ Vt,
                                               float* __restrict__ Wgt,
                                               bf16* __restrict__ Ctx) {
    const int tid = threadIdx.x;
    const int lane = tid & 63;
    const int wave = tid >> 6;                     // 0..3
    const int bh = blockIdx.x;                     // XCD = bh % 8
    const int qb = (blockIdx.y + (blockIdx.x & 3)) & 15;  // balanced per CU
    const int q0 = qb * 64 + wave * 16;
    const int lr = lane & 15;
    const int g = lane >> 4;
    const int lk8 = g * 8;
    const int rbase = g * 4;
    const int own_diag = q0 >> 4;                  // qb*4 + wave
    const int nch = qb + 1;                        // 64-row K chunks

    const bf16* Qb = Q + (size_t)bh * SS * DKK;
    const bf16* Kb = K + (size_t)bh * SS * DKK;
    const bf16* Vb = Vt + (size_t)bh * DKK * SS;
    float* Wrow = Wgt + ((size_t)bh * SS + q0) * SS;

    __shared__ __align__(16) bf16 Ks[2][64][64];
    __shared__ __align__(16) bf16 Vs[2][64][64];
    __shared__ __align__(16) bf16 Ps[4][16][40];

    const int skr = tid >> 2;
    const int sc0 = tid & 3;
    const int sw0 = (sc0 ^ (skr & 7)) * 8;
    const int sw1 = ((sc0 + 4) ^ (skr & 7)) * 8;

    bf16x8 qa0 = load8(Qb + (size_t)(q0 + lr) * DKK + lk8);
    bf16x8 qa1 = load8(Qb + (size_t)(q0 + lr) * DKK + 32 + lk8);
#pragma unroll
    for (int i = 0; i < 8; i++) {  // fold 1/sqrt(dk)=0.125 into Q (exact pow2)
        qa0[i] = (bf16)((float)qa0[i] * 0.125f);
        qa1[i] = (bf16)((float)qa1[i] * 0.125f);
    }

    const int rsw0 = (g ^ (lr & 7)) * 8;           // swizzled read offsets
    const int rsw1 = ((4 + g) ^ (lr & 7)) * 8;

    float sl[4] = {0.f, 0.f, 0.f, 0.f};

    // ---------------- pass 1: exp-sum (K only, double-buffered) -----------
    {
        bf16x8 ka = load8(Kb + (size_t)skr * DKK + sc0 * 8);
        bf16x8 kb_ = load8(Kb + (size_t)skr * DKK + (sc0 + 4) * 8);
        *reinterpret_cast<bf16x8*>(&Ks[0][skr][sw0]) = ka;
        *reinterpret_cast<bf16x8*>(&Ks[0][skr][sw1]) = kb_;
        __syncthreads();
        for (int ch = 0; ch < nch; ch++) {
            const int cur = ch & 1;
            if (ch + 1 < nch) {
                ka = load8(Kb + (size_t)((ch + 1) * 64 + skr) * DKK + sc0 * 8);
                kb_ = load8(Kb + (size_t)((ch + 1) * 64 + skr) * DKK + (sc0 + 4) * 8);
            }
#pragma unroll
            for (int t = 0; t < 4; t++) {
                const int kt = ch * 4 + t;
                if (kt <= own_diag) {   // wave-uniform
                    bf16x8 kb0 = *reinterpret_cast<const bf16x8*>(&Ks[cur][t * 16 + lr][rsw0]);
                    bf16x8 kb1 = *reinterpret_cast<const bf16x8*>(&Ks[cur][t * 16 + lr][rsw1]);
                    __builtin_amdgcn_s_setprio(1);
                    f32x4 sc = {};
                    sc = MFMA(qa0, kb0, sc);
                    sc = MFMA(qa1, kb1, sc);
                    __builtin_amdgcn_s_setprio(0);
                    const int kcol = kt * 16 + lr;
#pragma unroll
                    for (int r = 0; r < 4; r++)
                        sl[r] += (kcol <= q0 + rbase + r) ? __expf(sc[r]) : 0.f;
                }
            }
            if (ch + 1 < nch) {
                *reinterpret_cast<bf16x8*>(&Ks[cur ^ 1][skr][sw0]) = ka;
                *reinterpret_cast<bf16x8*>(&Ks[cur ^ 1][skr][sw1]) = kb_;
            }
            __syncthreads();
        }
    }
    float inv[4];
#pragma unroll
    for (int r = 0; r < 4; r++) {  // sum across the 16-lane group
        float t = sl[r];
        t += __shfl_xor(t, 1);
        t += __shfl_xor(t, 2);
        t += __shfl_xor(t, 4);
        t += __shfl_xor(t, 8);
        inv[r] = 1.f / t;
    }

    // ---------------- pass 2: weights write + PV (dbuf K+V) ---------------
    f32x4 oacc[4] = {};
    {
        bf16x8 ka = load8(Kb + (size_t)skr * DKK + sc0 * 8);
        bf16x8 kb_ = load8(Kb + (size_t)skr * DKK + (sc0 + 4) * 8);
        bf16x8 va = load8(Vb + (size_t)skr * SS + sc0 * 8);
        bf16x8 vb_ = load8(Vb + (size_t)skr * SS + (sc0 + 4) * 8);
        *reinterpret_cast<bf16x8*>(&Ks[0][skr][sw0]) = ka;
        *reinterpret_cast<bf16x8*>(&Ks[0][skr][sw1]) = kb_;
        *reinterpret_cast<bf16x8*>(&Vs[0][skr][sw0]) = va;
        *reinterpret_cast<bf16x8*>(&Vs[0][skr][sw1]) = vb_;
        __syncthreads();
        for (int ch = 0; ch < nch; ch++) {
            const int cur = ch & 1;
            if (ch + 1 < nch) {
                ka = load8(Kb + (size_t)((ch + 1) * 64 + skr) * DKK + sc0 * 8);
                kb_ = load8(Kb + (size_t)((ch + 1) * 64 + skr) * DKK + (sc0 + 4) * 8);
                va = load8(Vb + (size_t)skr * SS + (ch + 1) * 64 + sc0 * 8);
                vb_ = load8(Vb + (size_t)skr * SS + (ch + 1) * 64 + (sc0 + 4) * 8);
            }
#pragma unroll
            for (int t = 0; t < 4; t++) {
                const int kt = ch * 4 + t;
                if (kt <= own_diag) {
                    bf16x8 kb0 = *reinterpret_cast<const bf16x8*>(&Ks[cur][t * 16 + lr][rsw0]);
                    bf16x8 kb1 = *reinterpret_cast<const bf16x8*>(&Ks[cur][t * 16 + lr][rsw1]);
                    __builtin_amdgcn_s_setprio(1);
                    f32x4 sc = {};
                    sc = MFMA(qa0, kb0, sc);
                    sc = MFMA(qa1, kb1, sc);
                    __builtin_amdgcn_s_setprio(0);
                    const int kcol = kt * 16 + lr;
#pragma unroll
                    for (int r = 0; r < 4; r++) {
                        float p = (kcol <= q0 + rbase + r) ? __expf(sc[r]) * inv[r] : 0.f;
                        Ps[wave][rbase + r][(t & 1) * 16 + lr] = (bf16)p;
                    }
                } else {
#pragma unroll
                    for (int r = 0; r < 4; r++)
                        Ps[wave][rbase + r][(t & 1) * 16 + lr] = (bf16)0.f;
                }
                if (t & 1) {
                    // vectorized weight store: lane -> row lane>>2, 8 cols
                    const int colbase = ch * 64 + (t >> 1) * 32;
                    const int prow = lane >> 2;
                    const int pcol = (lane & 3) * 8;
                    bf16x8 pv8 = *reinterpret_cast<const bf16x8*>(&Ps[wave][prow][pcol]);
                    f32x4 w0, w1;
#pragma unroll
                    for (int i = 0; i < 4; i++) {
                        w0[i] = (float)pv8[i];
                        w1[i] = (float)pv8[4 + i];
                    }
                    float* dst = Wrow + (size_t)prow * SS + colbase + pcol;
                    *reinterpret_cast<f32x4*>(dst) = w0;
                    *reinterpret_cast<f32x4*>(dst + 4) = w1;
                    if (kt - 1 <= own_diag) {   // PV over the 32-col pair
                        const int p2 = t >> 1;
                        bf16x8 pf = *reinterpret_cast<const bf16x8*>(&Ps[wave][lr][lk8]);
                        __builtin_amdgcn_s_setprio(1);
#pragma unroll
                        for (int j = 0; j < 4; j++) {
                            bf16x8 vb = *reinterpret_cast<const bf16x8*>(
                                &Vs[cur][j * 16 + lr][((4 * p2 + g) ^ (lr & 7)) * 8]);
                            oacc[j] = MFMA(pf, vb, oacc[j]);
                        }
                        __builtin_amdgcn_s_setprio(0);
                    }
                }
            }
            if (ch + 1 < nch) {
                *reinterpret_cast<bf16x8*>(&Ks[cur ^ 1][skr][sw0]) = ka;
                *reinterpret_cast<bf16x8*>(&Ks[cur ^ 1][skr][sw1]) = kb_;
                *reinterpret_cast<bf16x8*>(&Vs[cur ^ 1][skr][sw0]) = va;
                *reinterpret_cast<bf16x8*>(&Vs[cur ^ 1][skr][sw1]) = vb_;
            }
            __syncthreads();
        }
    }

    const int b = bh >> 4, h = bh & 15;
#pragma unroll
    for (int j = 0; j < 4; j++)
#pragma unroll
        for (int r = 0; r < 4; r++) {
            int qrow = q0 + rbase + r;
            int col = h * 64 + j * 16 + lr;
            Ctx[((size_t)b * SS + qrow) * DD + col] = (bf16)oacc[j][r];
        }
}

// ---------------------------------------------------------------------------
extern "C" void kernel_launch(void* const* d_in, const int* in_sizes, int n_in,
                              void* d_out, int out_size, void* d_ws, size_t ws_size,
                              hipStream_t stream) {
    const float* x  = (const float*)d_in[0];
    const float* Wq = (const float*)d_in[1];
    const float* Wk = (const float*)d_in[2];
    const float* Wv = (const float*)d_in[3];
    const float* Wo = (const float*)d_in[4];

    float* out = (float*)d_out;                     // output (B,S,D) f32
    float* wgt = out + (size_t)BB * SS * DD;        // weights (B,H,S,S) f32

    const size_t MEG = 1024 * 1024;
    bf16* xb   = (bf16*)d_ws;         // x bf16        [0,4M)
    bf16* wcat = xb + 4 * MEG;        // Wq|Wk|Wv bf16 [4M,7M)
    bf16* wob  = xb + 7 * MEG;        // Wo bf16       [7M,8M)
    bf16* qws  = xb + 8 * MEG;        // Q  [b,h,s,dk]
    bf16* kws  = xb + 12 * MEG;       // K  [b,h,s,dk]
    bf16* vws  = xb + 16 * MEG;       // Vt [b,h,dk,s]
    bf16* cws  = xb + 20 * MEG;       // concat ctx [b,s,d]

    cvt_bf16<<<dim3(8192), 256, 0, stream>>>(x, Wq, Wk, Wv, Wo, xb);
    gemm_qkv<<<dim3(32, 24), 256, 0, stream>>>(xb, wcat, qws, kws, vws, wgt);
    attn<<<dim3(64, 16), 256, 0, stream>>>(qws, kws, vws, wgt, cws);
    gemm_out<<<dim3(64, 16), 256, 0, stream>>>(cws, wob, out);
}